// Round 3
// baseline (145.084 us; speedup 1.0000x reference)
//
#include <hip/hip_runtime.h>

// N=16384 rows, D=1024 fp32. loss = mean_r(1 - cos(pc[r], aug[r]))
// R3: three different wave-per-row schedules all flatlined at ~3 TB/s
// effective: per-row shuffle reduces (every 8KB) drained the memory queue,
// and the compiler refuses register double-buffering across shuffle chains.
// New shape (the m146 RMSNorm-style winner): block-per-8-rows, thread t owns
// float4 column t. Pure streaming accumulation into 24 per-thread scalars,
// ONE 24-chain shuffle reduce + LDS round-trip per 64KB. 2048 blocks =
// 8 blocks/CU resident; launch_bounds(256,8) caps VGPR at 64 -> 32 waves/CU.

#define N_ROWS 16384
#define DIM_V4 256              // 1024 floats = 256 float4
#define TPB 256
#define RPB 8                   // rows per block
#define BLOCKS (N_ROWS / RPB)   // 2048 = 8 blocks/CU exactly

__global__ __launch_bounds__(TPB, 8) void cos_rows_kernel(
    const float4* __restrict__ a, const float4* __restrict__ b,
    float* __restrict__ partial)
{
    const int t = threadIdx.x;
    const int wave = t >> 6;
    const int lane = t & 63;
    const size_t base = (size_t)blockIdx.x * RPB * DIM_V4 + t;
    const float4* ap = a + base;
    const float4* bp = b + base;

    float ab[RPB], aa[RPB], bb[RPB];

    // Streaming phase: 16 independent coalesced float4 loads, ~12cy FMA per
    // row pair between quads. No cross-lane ops -> memory queue stays full.
    #pragma unroll
    for (int r = 0; r < RPB; r += 2) {
        float4 x0 = ap[(r + 0) * DIM_V4];
        float4 y0 = bp[(r + 0) * DIM_V4];
        float4 x1 = ap[(r + 1) * DIM_V4];
        float4 y1 = bp[(r + 1) * DIM_V4];
        ab[r]     = x0.x*y0.x + x0.y*y0.y + x0.z*y0.z + x0.w*y0.w;
        aa[r]     = x0.x*x0.x + x0.y*x0.y + x0.z*x0.z + x0.w*x0.w;
        bb[r]     = y0.x*y0.x + y0.y*y0.y + y0.z*y0.z + y0.w*y0.w;
        ab[r + 1] = x1.x*y1.x + x1.y*y1.y + x1.z*y1.z + x1.w*y1.w;
        aa[r + 1] = x1.x*x1.x + x1.y*x1.y + x1.z*x1.z + x1.w*x1.w;
        bb[r + 1] = y1.x*y1.x + y1.y*y1.y + y1.z*y1.z + y1.w*y1.w;
    }

    // One reduce per 64KB: 24 independent butterfly chains (ILP-rich).
    #pragma unroll
    for (int off = 32; off > 0; off >>= 1) {
        #pragma unroll
        for (int r = 0; r < RPB; ++r) {
            ab[r] += __shfl_down(ab[r], off);
            aa[r] += __shfl_down(aa[r], off);
            bb[r] += __shfl_down(bb[r], off);
        }
    }

    // Cross-wave: 4 wave-partials per (row, value) via LDS.
    __shared__ float s[4][3 * RPB];
    __shared__ float srow[RPB];
    if (lane == 0) {
        #pragma unroll
        for (int r = 0; r < RPB; ++r) {
            s[wave][3 * r + 0] = ab[r];
            s[wave][3 * r + 1] = aa[r];
            s[wave][3 * r + 2] = bb[r];
        }
    }
    __syncthreads();
    if (t < RPB) {   // thread t finalizes row t
        float A = 0.f, B = 0.f, C = 0.f;
        #pragma unroll
        for (int w = 0; w < 4; ++w) {
            A += s[w][3 * t + 0];
            B += s[w][3 * t + 1];
            C += s[w][3 * t + 2];
        }
        float na = fmaxf(sqrtf(B), 1e-12f);
        float nb = fmaxf(sqrtf(C), 1e-12f);
        srow[t] = A / (na * nb);
    }
    __syncthreads();
    if (t == 0) {
        float tot = 0.f;
        #pragma unroll
        for (int r = 0; r < RPB; ++r) tot += srow[r];
        partial[blockIdx.x] = tot;
    }
}

__global__ __launch_bounds__(1024) void finalize_kernel(
    const float* __restrict__ partial, float* __restrict__ out)
{
    const int wave = threadIdx.x >> 6;
    const int lane = threadIdx.x & 63;
    float t = partial[threadIdx.x] + partial[threadIdx.x + 1024];  // BLOCKS=2048
    #pragma unroll
    for (int off = 32; off > 0; off >>= 1) t += __shfl_down(t, off);
    __shared__ float s[1024 / 64];
    if (lane == 0) s[wave] = t;
    __syncthreads();
    if (threadIdx.x == 0) {
        float tot = 0.0f;
        #pragma unroll
        for (int i = 0; i < 1024 / 64; ++i) tot += s[i];
        out[0] = 1.0f - tot / (float)N_ROWS;
    }
}

extern "C" void kernel_launch(void* const* d_in, const int* in_sizes, int n_in,
                              void* d_out, int out_size, void* d_ws, size_t ws_size,
                              hipStream_t stream) {
    const float4* pc  = (const float4*)d_in[0];
    const float4* aug = (const float4*)d_in[1];
    float* partial = (float*)d_ws;       // BLOCKS floats = 8 KiB scratch
    float* out = (float*)d_out;

    cos_rows_kernel<<<BLOCKS, TPB, 0, stream>>>(pc, aug, partial);
    finalize_kernel<<<1, 1024, 0, stream>>>(partial, out);
}

// Round 4
// 141.852 us; speedup vs baseline: 1.0228x; 1.0228x over previous
//
#include <hip/hip_runtime.h>

// N=16384 rows, D=1024 fp32. loss = mean_r(1 - cos(pc[r], aug[r]))
// R4: rounds 0-3 all flatlined at ~3.1 TB/s effective (= 5.1 B/cy/CU, half of
// the 10.2 the m13 copy sustains). Common cause: outstanding-load bytes per CU
// were register-bound (VGPR-capped to 1-2 float4/wave in R3) and the issue
// stream stopped during every reduce (block-wide convoys). Fix: stage via
// global_load_lds width=16 (NO dest VGPRs) -> whole 64KB block tile in flight
// in one burst; 2 resident blocks/CU = 128KB outstanding, compute of one block
// overlaps the other's burst. Waves 0-1 stage stream a, waves 2-3 stream b
// (decorrelates the a/b same-offset request pairing).

#define N_ROWS 16384
#define DIM_V4 256              // 1024 floats = 256 float4
#define TPB 256
#define RPB 8                   // rows per block
#define BLOCKS (N_ROWS / RPB)   // 2048 blocks, 8 per CU over kernel lifetime

typedef __attribute__((address_space(1))) const float4 gf4;
typedef __attribute__((address_space(3))) float4 lf4;

__global__ __launch_bounds__(TPB) void cos_rows_kernel(
    const float4* __restrict__ a, const float4* __restrict__ b,
    float* __restrict__ partial)
{
    __shared__ float4 sA[RPB][DIM_V4];   // 32 KiB
    __shared__ float4 sB[RPB][DIM_V4];   // 32 KiB
    __shared__ float sred[4][3 * RPB];
    __shared__ float srow[RPB];

    const int t = threadIdx.x;
    const int wave = t >> 6;
    const int lane = t & 63;

    // ---- Stage 64 KiB: wave w stages 16 KiB (16 x 1KiB instructions). ----
    // waves 0,1 -> stream a rows [0..4),[4..8); waves 2,3 -> stream b same.
    {
        const float4* gsrc = (wave < 2) ? a : b;
        float4* lds0 = (wave < 2) ? &sA[0][0] : &sB[0][0];
        const int rowbase = (wave & 1) * 4;                   // 4 rows = 16 KiB
        // per-lane global address (lane*16B), wave-uniform LDS base
        const float4* gp = gsrc + ((size_t)blockIdx.x * RPB + rowbase) * DIM_V4 + lane;
        float4* lp = lds0 + rowbase * DIM_V4;
        #pragma unroll
        for (int i = 0; i < 16; ++i) {
            // each instr: 64 lanes x 16B = 1 KiB, LDS dest = base + lane*16
            __builtin_amdgcn_global_load_lds((gf4*)(gp + i * 64),
                                             (lf4*)(lp + i * 64), 16, 0, 0);
        }
    }
    __syncthreads();   // drains vmcnt; other resident block's burst overlaps us

    // ---- Compute: thread t owns float4-column t of all 8 rows. ----
    float ab[RPB], aa[RPB], bb[RPB];
    #pragma unroll
    for (int r = 0; r < RPB; ++r) {
        float4 x = sA[r][t];
        float4 y = sB[r][t];
        ab[r] = x.x*y.x + x.y*y.y + x.z*y.z + x.w*y.w;
        aa[r] = x.x*x.x + x.y*x.y + x.z*x.z + x.w*x.w;
        bb[r] = y.x*y.x + y.y*y.y + y.z*y.z + y.w*y.w;
    }

    // ---- One reduce per 64 KiB: 24 independent butterfly chains. ----
    #pragma unroll
    for (int off = 32; off > 0; off >>= 1) {
        #pragma unroll
        for (int r = 0; r < RPB; ++r) {
            ab[r] += __shfl_down(ab[r], off);
            aa[r] += __shfl_down(aa[r], off);
            bb[r] += __shfl_down(bb[r], off);
        }
    }

    if (lane == 0) {
        #pragma unroll
        for (int r = 0; r < RPB; ++r) {
            sred[wave][3 * r + 0] = ab[r];
            sred[wave][3 * r + 1] = aa[r];
            sred[wave][3 * r + 2] = bb[r];
        }
    }
    __syncthreads();
    if (t < RPB) {   // thread t finalizes row t
        float A = 0.f, B = 0.f, C = 0.f;
        #pragma unroll
        for (int w = 0; w < 4; ++w) {
            A += sred[w][3 * t + 0];
            B += sred[w][3 * t + 1];
            C += sred[w][3 * t + 2];
        }
        float na = fmaxf(sqrtf(B), 1e-12f);
        float nb = fmaxf(sqrtf(C), 1e-12f);
        srow[t] = A / (na * nb);
    }
    __syncthreads();
    if (t == 0) {
        float tot = 0.f;
        #pragma unroll
        for (int r = 0; r < RPB; ++r) tot += srow[r];
        partial[blockIdx.x] = tot;
    }
}

__global__ __launch_bounds__(1024) void finalize_kernel(
    const float* __restrict__ partial, float* __restrict__ out)
{
    const int wave = threadIdx.x >> 6;
    const int lane = threadIdx.x & 63;
    float t = partial[threadIdx.x] + partial[threadIdx.x + 1024];  // BLOCKS=2048
    #pragma unroll
    for (int off = 32; off > 0; off >>= 1) t += __shfl_down(t, off);
    __shared__ float s[1024 / 64];
    if (lane == 0) s[wave] = t;
    __syncthreads();
    if (threadIdx.x == 0) {
        float tot = 0.0f;
        #pragma unroll
        for (int i = 0; i < 1024 / 64; ++i) tot += s[i];
        out[0] = 1.0f - tot / (float)N_ROWS;
    }
}

extern "C" void kernel_launch(void* const* d_in, const int* in_sizes, int n_in,
                              void* d_out, int out_size, void* d_ws, size_t ws_size,
                              hipStream_t stream) {
    const float4* pc  = (const float4*)d_in[0];
    const float4* aug = (const float4*)d_in[1];
    float* partial = (float*)d_ws;       // BLOCKS floats = 8 KiB scratch
    float* out = (float*)d_out;

    cos_rows_kernel<<<BLOCKS, TPB, 0, stream>>>(pc, aug, partial);
    finalize_kernel<<<1, 1024, 0, stream>>>(partial, out);
}